// Round 4
// baseline (812.757 us; speedup 1.0000x reference)
//
#include <hip/hip_runtime.h>
#include <hip/hip_bf16.h>

#define B_   4
#define LQ_  4096
#define LS_  4096
#define DH_  1024
#define BQ_  64
#define BS_  256
#define NT_  (LS_/BS_)   /* 16 */
#define NTH  512

typedef __bf16 bf16x8 __attribute__((ext_vector_type(8)));
typedef float  f32x4  __attribute__((ext_vector_type(4)));

__device__ __forceinline__ unsigned short f2bf(float f) {
  union { __bf16 h; unsigned short u; } cv;
  cv.h = (__bf16)f;
  return cv.u;
}

// ---- fp32 S -> bf16 Sb (row-major [b][s][d]) + bf16 STb (transposed [b][d][s]) ----
__global__ __launch_bounds__(256) void cvt_kernel(const float* __restrict__ S,
                                                  __bf16* __restrict__ Sb,
                                                  __bf16* __restrict__ STb)
{
  __shared__ unsigned short tile[64][72];
  const int b  = blockIdx.z;
  const int dt = blockIdx.y;   // 0..15  (64 d each)
  const int st = blockIdx.x;   // 0..63  (64 s each)
  const int tid = threadIdx.x;
  const float* Sbase = S + ((size_t)b*LS_ + (size_t)st*64)*DH_ + dt*64;

  #pragma unroll
  for (int k = 0; k < 4; ++k) {
    int fi  = tid + k*256;
    int row = fi >> 4;          // 0..63 (s within tile)
    int c4  = fi & 15;
    float4 v = *reinterpret_cast<const float4*>(Sbase + (size_t)row*DH_ + c4*4);
    ushort4 h;
    h.x = f2bf(v.x); h.y = f2bf(v.y); h.z = f2bf(v.z); h.w = f2bf(v.w);
    *reinterpret_cast<ushort4*>((unsigned short*)Sb +
        ((size_t)b*LS_ + (size_t)st*64 + row)*DH_ + dt*64 + c4*4) = h;
    *reinterpret_cast<ushort4*>(&tile[row][c4*4]) = h;
  }
  __syncthreads();
  #pragma unroll
  for (int k = 0; k < 4; ++k) {
    int fo = tid + k*256;
    int dr = fo >> 4;           // 0..63 (d within tile)
    int s4 = fo & 15;
    ushort4 h;
    h.x = tile[s4*4+0][dr];
    h.y = tile[s4*4+1][dr];
    h.z = tile[s4*4+2][dr];
    h.w = tile[s4*4+3][dr];
    *reinterpret_cast<ushort4*>((unsigned short*)STb +
        ((size_t)b*DH_ + (size_t)dt*64 + dr)*LS_ + st*64 + s4*4) = h;
  }
}

// ---------------- fused flash attention, m==0 softmax ----------------
// Q resident in LDS (staged once); K/V direct global->register rings.
__global__ __launch_bounds__(NTH, 2) void attn_kernel(
    const float* __restrict__ Qg,
    const __bf16* __restrict__ Sb,
    const __bf16* __restrict__ STb,
    float* __restrict__ Og)
{
  __shared__ __align__(16) unsigned char qlds[BQ_*DH_*2];   // 131072 B
  __shared__ __align__(16) unsigned char plds[BQ_*BS_*2];   // 32768 B (P; epilogue l-reduce)

  const int tid = threadIdx.x;
  const int w  = tid >> 6;
  const int l  = tid & 63;
  const int lg = l >> 4;
  const int lr = l & 15;

  // XCD swizzle: batch b -> XCD pair {2b,2b+1}; same-XCD blocks share S tiles in L2
  const int n    = blockIdx.x;          // 0..255
  const int xcd  = n & 7;
  const int slot = n >> 3;              // 0..31
  const int b    = xcd >> 1;
  const int qt   = (xcd & 1)*32 + slot; // 0..63

  const float*  Qbase = Qg + ((size_t)b*LQ_ + (size_t)qt*BQ_)*DH_;
  const __bf16* Sbb   = Sb  + (size_t)b*LS_*DH_;
  const __bf16* STbb  = STb + (size_t)b*DH_*LS_;

  // ---- stage Q tile fp32 -> bf16 into LDS (once; swizzled rows of 2048 B) ----
  #pragma unroll 4
  for (int it = 0; it < 32; ++it) {
    int fi  = tid + it*NTH;       // [0, 16384) float4 units
    int row = fi >> 8;
    int c4  = fi & 255;
    float4 v = *reinterpret_cast<const float4*>(Qbase + (size_t)row*DH_ + c4*4);
    ushort4 h;
    h.x = f2bf(v.x); h.y = f2bf(v.y); h.z = f2bf(v.z); h.w = f2bf(v.w);
    int byte = (row*2048 + c4*8) ^ ((row & 7) << 4);
    *reinterpret_cast<ushort4*>(qlds + byte) = h;
  }

  f32x4 Oacc[4][8];
  #pragma unroll
  for (int i = 0; i < 4; ++i)
    #pragma unroll
    for (int j = 0; j < 8; ++j)
      Oacc[i][j] = (f32x4){0.f, 0.f, 0.f, 0.f};
  float l_acc[4][4];
  #pragma unroll
  for (int i = 0; i < 4; ++i)
    #pragma unroll
    for (int j = 0; j < 4; ++j)
      l_acc[i][j] = 0.f;

  const int swzA = (lr & 7) << 4;

  // K-frag ring: wave-unique s rows [32w, 32w+32); frag ns in {0,1}
  bf16x8 bq[4][2];
  // V-frag ring
  bf16x8 bv[8];

  auto ld_bq = [&](int t, int kk, bf16x8* dst) {
    const __bf16* p = Sbb + (size_t)(t*BS_ + w*32 + lr)*DH_ + kk*32 + lg*8;
    dst[0] = *reinterpret_cast<const bf16x8*>(p);
    dst[1] = *reinterpret_cast<const bf16x8*>(p + 16*DH_);
  };
  auto ld_bv = [&](int t, int ks, int nf) -> bf16x8 {
    return *reinterpret_cast<const bf16x8*>(
        STbb + (size_t)(w*128 + nf*16 + lr)*LS_ + t*BS_ + ks*32 + lg*8);
  };

  // K-ring prologue for t=0 (depth 4, distance 3)
  ld_bq(0, 0, bq[0]); ld_bq(0, 1, bq[1]); ld_bq(0, 2, bq[2]);
  __syncthreads();    // Q staged

  for (int t = 0; t < NT_; ++t) {
    // ================= QK^T: acc[64 q][wave's 32 s] over d=1024 =================
    f32x4 acc[4][2];
    #pragma unroll
    for (int i = 0; i < 4; ++i)
      #pragma unroll
      for (int j = 0; j < 2; ++j)
        acc[i][j] = (f32x4){0.f, 0.f, 0.f, 0.f};

    #pragma unroll
    for (int kk = 0; kk < 32; ++kk) {
      if (kk < 29) ld_bq(t, kk + 3, bq[(kk + 3) & 3]);
      bf16x8 aq[4];
      #pragma unroll
      for (int mq = 0; mq < 4; ++mq) {
        int row  = mq*16 + lr;
        int byte = row*2048 + ((kk*64 + lg*16) ^ swzA);
        aq[mq] = *reinterpret_cast<const bf16x8*>(qlds + byte);
      }
      __builtin_amdgcn_s_setprio(1);
      #pragma unroll
      for (int mq = 0; mq < 4; ++mq)
        #pragma unroll
        for (int ns = 0; ns < 2; ++ns)
          acc[mq][ns] = __builtin_amdgcn_mfma_f32_16x16x32_bf16(aq[mq], bq[kk & 3][ns], acc[mq][ns], 0, 0, 0);
      __builtin_amdgcn_s_setprio(0);
    }

    // ================= P = exp2(logit*log2e/32), write P to LDS, accumulate l =================
    const float SCL = 0.04508422f;   // (1/32) * log2(e)
    #pragma unroll
    for (int mq = 0; mq < 4; ++mq)
      #pragma unroll
      for (int ns = 0; ns < 2; ++ns)
        #pragma unroll
        for (int j = 0; j < 4; ++j) {
          float p = exp2f(acc[mq][ns][j] * SCL);
          l_acc[mq][j] += p;
          int q = mq*16 + lg*4 + j;
          int s = w*32 + ns*16 + lr;
          int byte = q*512 + ((s*2) ^ ((q & 7) << 4));
          *reinterpret_cast<__bf16*>(plds + byte) = (__bf16)p;
        }

    // V-ring prologue (independent of P; hides under exp/ds_write + barrier)
    #pragma unroll
    for (int i = 0; i < 7; ++i)
      bv[i] = ld_bv(t, i >> 3, i & 7);

    __syncthreads();   // #1: P visible

    // ================= PV: O[64 q][wave's 128 d] += P[64][256] @ V =================
    bf16x8 pa[4];
    #pragma unroll
    for (int i = 0; i < 64; ++i) {
      const int ks = i >> 3, nf = i & 7;
      if (i < 57) { const int i7 = i + 7; bv[i7 & 7] = ld_bv(t, i7 >> 3, i7 & 7); }
      // K-ring prologue for t+1, issued in the PV tail
      if (i >= 57 && i < 60 && t + 1 < NT_) ld_bq(t + 1, i - 57, bq[i - 57]);
      if (nf == 0) {
        #pragma unroll
        for (int mq = 0; mq < 4; ++mq) {
          int row  = mq*16 + lr;
          int byte = row*512 + ((ks*64 + lg*16) ^ swzA);
          pa[mq] = *reinterpret_cast<const bf16x8*>(plds + byte);
        }
      }
      __builtin_amdgcn_s_setprio(1);
      #pragma unroll
      for (int mq = 0; mq < 4; ++mq)
        Oacc[mq][nf] = __builtin_amdgcn_mfma_f32_16x16x32_bf16(pa[mq], bv[i & 7], Oacc[mq][nf], 0, 0, 0);
      __builtin_amdgcn_s_setprio(0);
    }

    __syncthreads();   // #2: P region free for next tile
  }

  // ================= epilogue: combine per-wave l partials, write O =================
  #pragma unroll
  for (int mq = 0; mq < 4; ++mq)
    #pragma unroll
    for (int j = 0; j < 4; ++j) {
      float v = l_acc[mq][j];
      v += __shfl_xor(v, 1);
      v += __shfl_xor(v, 2);
      v += __shfl_xor(v, 4);
      v += __shfl_xor(v, 8);
      l_acc[mq][j] = v;
    }
  float* lred = (float*)plds;
  if (lr == 0) {
    #pragma unroll
    for (int mq = 0; mq < 4; ++mq)
      #pragma unroll
      for (int j = 0; j < 4; ++j)
        lred[w*64 + mq*16 + lg*4 + j] = l_acc[mq][j];
  }
  __syncthreads();

  float* Ob = Og + ((size_t)b*LQ_ + (size_t)qt*BQ_)*DH_;
  #pragma unroll
  for (int mq = 0; mq < 4; ++mq)
    #pragma unroll
    for (int j = 0; j < 4; ++j) {
      int q = mq*16 + lg*4 + j;
      float s = 0.f;
      #pragma unroll
      for (int ww = 0; ww < 8; ++ww) s += lred[ww*64 + q];
      float rinv = 1.0f / s;
      #pragma unroll
      for (int nf = 0; nf < 8; ++nf)
        Ob[(size_t)q*DH_ + w*128 + nf*16 + lr] = Oacc[mq][nf][j] * rinv;
    }
}

// ---------------- correctness-only fallback (ws too small; never expected) ----------------
__global__ void attn_naive(const float* __restrict__ Q, const float* __restrict__ S,
                           float* __restrict__ O)
{
  const int row = blockIdx.x;
  const int b = row >> 12, q = row & 4095;
  const float* qp = Q + ((size_t)b*LQ_ + q)*DH_;
  const float* sp = S + (size_t)b*LS_*DH_;
  __shared__ float qs[DH_];
  __shared__ float osum[DH_];
  __shared__ float lsum;
  for (int i = threadIdx.x; i < DH_; i += 256) { qs[i] = qp[i]; osum[i] = 0.f; }
  if (threadIdx.x == 0) lsum = 0.f;
  __syncthreads();
  float lpart = 0.f;
  for (int s0 = threadIdx.x; s0 < LS_; s0 += 256) {
    const float* sr = sp + (size_t)s0*DH_;
    float dot = 0.f;
    for (int d = 0; d < DH_; ++d) dot += qs[d]*sr[d];
    float p = __expf(dot * 0.03125f);
    lpart += p;
    for (int d = 0; d < DH_; ++d) atomicAdd(&osum[d], p*sr[d]);
  }
  atomicAdd(&lsum, lpart);
  __syncthreads();
  float rinv = 1.0f / lsum;
  float* op = O + ((size_t)b*LQ_ + q)*DH_;
  for (int i = threadIdx.x; i < DH_; i += 256) op[i] = osum[i]*rinv;
}

extern "C" void kernel_launch(void* const* d_in, const int* in_sizes, int n_in,
                              void* d_out, int out_size, void* d_ws, size_t ws_size,
                              hipStream_t stream)
{
  const float* Q = (const float*)d_in[0];
  const float* S = (const float*)d_in[1];
  float* out = (float*)d_out;

  const size_t elems = (size_t)B_ * LS_ * DH_;
  const size_t need  = elems * 2 /*bf16*/ * 2 /*Sb + STb*/;   // 64 MiB

  if (ws_size >= need) {
    __bf16* Sb  = (__bf16*)d_ws;
    __bf16* STb = Sb + elems;
    cvt_kernel<<<dim3(64, 16, 4), 256, 0, stream>>>(S, Sb, STb);
    attn_kernel<<<dim3(256), NTH, 0, stream>>>(Q, Sb, STb, out);
  } else {
    attn_naive<<<dim3(B_*LQ_), 256, 0, stream>>>(Q, S, out);
  }
}

// Round 5
// 541.603 us; speedup vs baseline: 1.5007x; 1.5007x over previous
//
#include <hip/hip_runtime.h>
#include <hip/hip_bf16.h>

#define B_   4
#define LQ_  4096
#define LS_  4096
#define DH_  1024
#define BQ_  64
#define BS_  256
#define NT_  (LS_/BS_)   /* 16 */
#define NTH  512

typedef __bf16 bf16x8 __attribute__((ext_vector_type(8)));
typedef float  f32x4  __attribute__((ext_vector_type(4)));
typedef float  f32x16 __attribute__((ext_vector_type(16)));

#define WAITL()  asm volatile("s_waitcnt lgkmcnt(0)" ::: "memory")
#define BAR()    __builtin_amdgcn_s_barrier()

__device__ __forceinline__ unsigned short f2bf(float f) {
  union { __bf16 h; unsigned short u; } cv;
  cv.h = (__bf16)f;
  return cv.u;
}
__device__ __forceinline__ bf16x8 cvt8(f32x4 a, f32x4 b) {
  bf16x8 r;
  r[0] = (__bf16)a[0]; r[1] = (__bf16)a[1]; r[2] = (__bf16)a[2]; r[3] = (__bf16)a[3];
  r[4] = (__bf16)b[0]; r[5] = (__bf16)b[1]; r[6] = (__bf16)b[2]; r[7] = (__bf16)b[3];
  return r;
}

// ---- fp32 S -> bf16 Sb (row-major [b][s][d]) + bf16 STb (transposed [b][d][s]) ----
__global__ __launch_bounds__(256) void cvt_kernel(const float* __restrict__ S,
                                                  __bf16* __restrict__ Sb,
                                                  __bf16* __restrict__ STb)
{
  __shared__ unsigned short tile[64][72];
  const int b  = blockIdx.z;
  const int dt = blockIdx.y;   // 0..15  (64 d each)
  const int st = blockIdx.x;   // 0..63  (64 s each)
  const int tid = threadIdx.x;
  const float* Sbase = S + ((size_t)b*LS_ + (size_t)st*64)*DH_ + dt*64;

  #pragma unroll
  for (int k = 0; k < 4; ++k) {
    int fi  = tid + k*256;
    int row = fi >> 4;
    int c4  = fi & 15;
    float4 v = *reinterpret_cast<const float4*>(Sbase + (size_t)row*DH_ + c4*4);
    ushort4 h;
    h.x = f2bf(v.x); h.y = f2bf(v.y); h.z = f2bf(v.z); h.w = f2bf(v.w);
    *reinterpret_cast<ushort4*>((unsigned short*)Sb +
        ((size_t)b*LS_ + (size_t)st*64 + row)*DH_ + dt*64 + c4*4) = h;
    *reinterpret_cast<ushort4*>(&tile[row][c4*4]) = h;
  }
  __syncthreads();
  #pragma unroll
  for (int k = 0; k < 4; ++k) {
    int fo = tid + k*256;
    int dr = fo >> 4;
    int s4 = fo & 15;
    ushort4 h;
    h.x = tile[s4*4+0][dr];
    h.y = tile[s4*4+1][dr];
    h.z = tile[s4*4+2][dr];
    h.w = tile[s4*4+3][dr];
    *reinterpret_cast<ushort4*>((unsigned short*)STb +
        ((size_t)b*DH_ + (size_t)dt*64 + dr)*LS_ + st*64 + s4*4) = h;
  }
}

// ---------------- fused flash attention, m==0 softmax ----------------
// QK^T: 32x32x16 MFMA, Q in lane-linear LDS (conflict-free b128 reads).
// PV:   16x16x32 MFMA, P via LDS, V direct global->register ring.
__global__ __launch_bounds__(NTH, 2) void attn_kernel(
    const float* __restrict__ Qg,
    const __bf16* __restrict__ Sb,
    const __bf16* __restrict__ STb,
    float* __restrict__ Og)
{
  __shared__ __align__(16) unsigned char qlds[131072];  // [qf:2][kk:64][lane:64]*16B
  __shared__ __align__(16) unsigned char plds[32768];   // P [64 q][256 s] bf16 swizzled

  const int tid = threadIdx.x;
  const int w  = tid >> 6;
  const int l  = tid & 63;
  const int lg = l >> 4;
  const int lr = l & 15;
  const int sl = l & 31;
  const int sh = l >> 5;

  // XCD swizzle: batch -> XCD pair; same-XCD blocks share K/V tiles in L2
  const int n    = blockIdx.x;
  const int xcd  = n & 7;
  const int slot = n >> 3;
  const int b    = xcd >> 1;
  const int qt   = (xcd & 1)*32 + slot;

  const float*  Qbase = Qg + ((size_t)b*LQ_ + (size_t)qt*BQ_)*DH_;
  const __bf16* Sbb   = Sb  + (size_t)b*LS_*DH_;
  const __bf16* STbb  = STb + (size_t)b*DH_*LS_;

  // K-frag: lane holds K[s = t*256 + w*32 + sl][kk*16 + sh*8 .. +8)
  bf16x8 bk[4];
  auto ld_bk = [&](int t, int kk) -> bf16x8 {
    return *reinterpret_cast<const bf16x8*>(
        Sbb + (size_t)(t*BS_ + w*32 + sl)*DH_ + kk*16 + sh*8);
  };
  // V-frag: lane holds V^T[d = w*128 + nf*16 + lr][s = t*256 + ks*32 + lg*8 .. +8)
  bf16x8 bv[4];
  auto ld_bv = [&](int t, int ks, int nf) -> bf16x8 {
    return *reinterpret_cast<const bf16x8*>(
        STbb + (size_t)(w*128 + nf*16 + lr)*LS_ + t*BS_ + ks*32 + lg*8);
  };

  // K-ring prologue for t=0 (in flight across Q-stage + barrier)
  bk[0] = ld_bk(0, 0); bk[1] = ld_bk(0, 1); bk[2] = ld_bk(0, 2);

  // ---- stage Q fp32 -> bf16 into lane-linear fragment layout (once) ----
  #pragma unroll
  for (int it = 0; it < 16; ++it) {
    int u  = tid + it*NTH;          // 0..8191 fragment units of 16 B
    int qf = u >> 12;
    int kk = (u >> 6) & 63;
    int ll = u & 63;
    int q  = qf*32 + (ll & 31);
    int d  = kk*16 + (ll >> 5)*8;
    const float* p = Qbase + (size_t)q*DH_ + d;
    f32x4 v0 = *reinterpret_cast<const f32x4*>(p);
    f32x4 v1 = *reinterpret_cast<const f32x4*>(p + 4);
    *reinterpret_cast<bf16x8*>(qlds + (size_t)u*16) = cvt8(v0, v1);
  }

  f32x4 Oacc[4][8];
  #pragma unroll
  for (int i = 0; i < 4; ++i)
    #pragma unroll
    for (int j = 0; j < 8; ++j)
      Oacc[i][j] = (f32x4){0.f, 0.f, 0.f, 0.f};
  f32x4 lacc[4];
  #pragma unroll
  for (int i = 0; i < 4; ++i) lacc[i] = (f32x4){0.f, 0.f, 0.f, 0.f};

  bf16x8 ones;
  #pragma unroll
  for (int e = 0; e < 8; ++e) ones[e] = (__bf16)1.0f;

  WAITL();
  BAR();   // Q staged (global K-ring loads stay in flight)

  for (int t = 0; t < NT_; ++t) {
    // ================= QK^T: C[64 q][wave's 32 s], 32x32x16 =================
    f32x16 qk0, qk1;
    #pragma unroll
    for (int r = 0; r < 16; ++r) { qk0[r] = 0.f; qk1[r] = 0.f; }

    bf16x8 aqA0 = *reinterpret_cast<const bf16x8*>(qlds + l*16);
    bf16x8 aqA1 = *reinterpret_cast<const bf16x8*>(qlds + 65536 + l*16);

    #pragma unroll
    for (int kk = 0; kk < 64; ++kk) {
      if (kk < 61) bk[(kk + 3) & 3] = ld_bk(t, kk + 3);
      bf16x8 aqN0, aqN1;
      if (kk < 63) {
        aqN0 = *reinterpret_cast<const bf16x8*>(qlds + (kk + 1)*1024 + l*16);
        aqN1 = *reinterpret_cast<const bf16x8*>(qlds + 65536 + (kk + 1)*1024 + l*16);
      }
      __builtin_amdgcn_s_setprio(1);
      qk0 = __builtin_amdgcn_mfma_f32_32x32x16_bf16(aqA0, bk[kk & 3], qk0, 0, 0, 0);
      qk1 = __builtin_amdgcn_mfma_f32_32x32x16_bf16(aqA1, bk[kk & 3], qk1, 0, 0, 0);
      __builtin_amdgcn_s_setprio(0);
      if (kk < 63) { aqA0 = aqN0; aqA1 = aqN1; }
    }

    // ================= P = exp2(logit*scl) -> LDS (conflict-free writes) =================
    const float SCL = 0.04508422f;   // (1/32) * log2(e)
    #pragma unroll
    for (int r = 0; r < 16; ++r) {
      int qrow = (r & 3) + 8*(r >> 2) + 4*sh;
      int s    = w*32 + sl;
      {
        float p = exp2f(qk0[r] * SCL);
        int q = qrow;
        *reinterpret_cast<__bf16*>(plds + q*512 + ((s*2) ^ ((q & 7) << 4))) = (__bf16)p;
      }
      {
        float p = exp2f(qk1[r] * SCL);
        int q = 32 + qrow;
        *reinterpret_cast<__bf16*>(plds + q*512 + ((s*2) ^ ((q & 7) << 4))) = (__bf16)p;
      }
    }

    // V-ring prologue (global; independent of P)
    bv[0] = ld_bv(t, 0, 0); bv[1] = ld_bv(t, 0, 1); bv[2] = ld_bv(t, 0, 2);
    WAITL();
    BAR();   // #1: P visible to all waves

    // ================= PV: O[64 q][wave's 128 d] += P[64][256] @ V =================
    bf16x8 pa0, pa1, pa2, pa3, pn0, pn1, pn2, pn3;
    auto ldP = [&](int mq, int ks) -> bf16x8 {
      int q = mq*16 + lr;
      return *reinterpret_cast<const bf16x8*>(
          plds + q*512 + ((ks*64 + lg*16) ^ ((q & 7) << 4)));
    };
    pa0 = ldP(0, 0); pa1 = ldP(1, 0); pa2 = ldP(2, 0); pa3 = ldP(3, 0);

    #pragma unroll
    for (int ks = 0; ks < 8; ++ks) {
      #pragma unroll
      for (int nf = 0; nf < 8; ++nf) {
        const int i = ks*8 + nf;
        if (i < 61) bv[(i + 3) & 3] = ld_bv(t, (i + 3) >> 3, (i + 3) & 7);
        if (t + 1 < NT_ && i >= 61) bk[i - 61] = ld_bk(t + 1, i - 61);
        if (ks < 7) {
          if (nf == 1) pn0 = ldP(0, ks + 1);
          if (nf == 2) pn1 = ldP(1, ks + 1);
          if (nf == 3) pn2 = ldP(2, ks + 1);
          if (nf == 4) pn3 = ldP(3, ks + 1);
        }
        if (nf == 0 && w == 0) {
          lacc[0] = __builtin_amdgcn_mfma_f32_16x16x32_bf16(pa0, ones, lacc[0], 0, 0, 0);
          lacc[1] = __builtin_amdgcn_mfma_f32_16x16x32_bf16(pa1, ones, lacc[1], 0, 0, 0);
          lacc[2] = __builtin_amdgcn_mfma_f32_16x16x32_bf16(pa2, ones, lacc[2], 0, 0, 0);
          lacc[3] = __builtin_amdgcn_mfma_f32_16x16x32_bf16(pa3, ones, lacc[3], 0, 0, 0);
        }
        __builtin_amdgcn_s_setprio(1);
        Oacc[0][nf] = __builtin_amdgcn_mfma_f32_16x16x32_bf16(pa0, bv[i & 3], Oacc[0][nf], 0, 0, 0);
        Oacc[1][nf] = __builtin_amdgcn_mfma_f32_16x16x32_bf16(pa1, bv[i & 3], Oacc[1][nf], 0, 0, 0);
        Oacc[2][nf] = __builtin_amdgcn_mfma_f32_16x16x32_bf16(pa2, bv[i & 3], Oacc[2][nf], 0, 0, 0);
        Oacc[3][nf] = __builtin_amdgcn_mfma_f32_16x16x32_bf16(pa3, bv[i & 3], Oacc[3][nf], 0, 0, 0);
        __builtin_amdgcn_s_setprio(0);
      }
      if (ks < 7) { pa0 = pn0; pa1 = pn1; pa2 = pn2; pa3 = pn3; }
    }
    BAR();   // #2: P region free for next tile's writes
  }

  // ================= epilogue: l from wave-0 ones-MFMA, write O =================
  float* lred = (float*)plds;
  if (w == 0 && lr == 0) {
    #pragma unroll
    for (int mq = 0; mq < 4; ++mq)
      #pragma unroll
      for (int j = 0; j < 4; ++j)
        lred[mq*16 + lg*4 + j] = lacc[mq][j];
  }
  WAITL();
  BAR();

  float* Ob = Og + ((size_t)b*LQ_ + (size_t)qt*BQ_)*DH_;
  #pragma unroll
  for (int mq = 0; mq < 4; ++mq)
    #pragma unroll
    for (int j = 0; j < 4; ++j) {
      int q = mq*16 + lg*4 + j;
      float rinv = 1.0f / lred[q];
      #pragma unroll
      for (int nf = 0; nf < 8; ++nf)
        Ob[(size_t)q*DH_ + w*128 + nf*16 + lr] = Oacc[mq][nf][j] * rinv;
    }
}

// ---------------- correctness-only fallback (ws too small; never expected) ----------------
__global__ void attn_naive(const float* __restrict__ Q, const float* __restrict__ S,
                           float* __restrict__ O)
{
  const int row = blockIdx.x;
  const int b = row >> 12, q = row & 4095;
  const float* qp = Q + ((size_t)b*LQ_ + q)*DH_;
  const float* sp = S + (size_t)b*LS_*DH_;
  __shared__ float qs[DH_];
  __shared__ float osum[DH_];
  __shared__ float lsum;
  for (int i = threadIdx.x; i < DH_; i += 256) { qs[i] = qp[i]; osum[i] = 0.f; }
  if (threadIdx.x == 0) lsum = 0.f;
  __syncthreads();
  float lpart = 0.f;
  for (int s0 = threadIdx.x; s0 < LS_; s0 += 256) {
    const float* sr = sp + (size_t)s0*DH_;
    float dot = 0.f;
    for (int d = 0; d < DH_; ++d) dot += qs[d]*sr[d];
    float p = __expf(dot * 0.03125f);
    lpart += p;
    for (int d = 0; d < DH_; ++d) atomicAdd(&osum[d], p*sr[d]);
  }
  atomicAdd(&lsum, lpart);
  __syncthreads();
  float rinv = 1.0f / lsum;
  float* op = O + ((size_t)b*LQ_ + q)*DH_;
  for (int i = threadIdx.x; i < DH_; i += 256) op[i] = osum[i]*rinv;
}

extern "C" void kernel_launch(void* const* d_in, const int* in_sizes, int n_in,
                              void* d_out, int out_size, void* d_ws, size_t ws_size,
                              hipStream_t stream)
{
  const float* Q = (const float*)d_in[0];
  const float* S = (const float*)d_in[1];
  float* out = (float*)d_out;

  const size_t elems = (size_t)B_ * LS_ * DH_;
  const size_t need  = elems * 2 /*bf16*/ * 2 /*Sb + STb*/;   // 64 MiB

  if (ws_size >= need) {
    __bf16* Sb  = (__bf16*)d_ws;
    __bf16* STb = Sb + elems;
    cvt_kernel<<<dim3(64, 16, 4), 256, 0, stream>>>(S, Sb, STb);
    attn_kernel<<<dim3(256), NTH, 0, stream>>>(Q, Sb, STb, out);
  } else {
    attn_naive<<<dim3(B_*LQ_), 256, 0, stream>>>(Q, S, out);
  }
}

// Round 6
// 301.991 us; speedup vs baseline: 2.6913x; 1.7934x over previous
//
#include <hip/hip_runtime.h>
#include <hip/hip_bf16.h>

#define B_   4
#define LQ_  4096
#define LS_  4096
#define DH_  1024
#define BQ_  64
#define BS_  256
#define NT_  (LS_/BS_)   /* 16 */
#define NTH  512

typedef __bf16 bf16x8 __attribute__((ext_vector_type(8)));
typedef float  f32x4  __attribute__((ext_vector_type(4)));
typedef float  f32x16 __attribute__((ext_vector_type(16)));
typedef unsigned char u8;

#define WAITL()  asm volatile("s_waitcnt lgkmcnt(0)" ::: "memory")
#define BAR()    __builtin_amdgcn_s_barrier()

__device__ __forceinline__ unsigned short f2bf(float f) {
  union { __bf16 h; unsigned short u; } cv;
  cv.h = (__bf16)f;
  return cv.u;
}
__device__ __forceinline__ bf16x8 cvt8(f32x4 a, f32x4 b) {
  bf16x8 r;
  r[0] = (__bf16)a[0]; r[1] = (__bf16)a[1]; r[2] = (__bf16)a[2]; r[3] = (__bf16)a[3];
  r[4] = (__bf16)b[0]; r[5] = (__bf16)b[1]; r[6] = (__bf16)b[2]; r[7] = (__bf16)b[3];
  return r;
}

// ---- fp32 S -> fragment-major bf16 layouts (wave-contiguous 1KB ring loads) ----
// Kf unit addr: (((b*16+t)*8 + w)*64 + kk)*1024 + lane*16
//    lane=(sh,sl): value S[b][t*256 + w*32 + sl][kk*16 + sh*8 + e], e=0..7
// Vf unit addr: (((b*16+t)*8 + w)*64 + ks*8+nf)*1024 + lane*16
//    lane=(lg,lr): value S[b][t*256 + ks*32 + lg*8 + e][w*128 + nf*16 + lr]
__global__ __launch_bounds__(256) void cvt_kernel(const float* __restrict__ S,
                                                  u8* __restrict__ Kf,
                                                  u8* __restrict__ Vf)
{
  __shared__ unsigned short tile[64][72];
  const int b  = blockIdx.z;
  const int dt = blockIdx.y;   // 0..15  (64 d each)
  const int st = blockIdx.x;   // 0..63  (64 s each)
  const int tid = threadIdx.x;
  const int t  = st >> 2;
  const float* Sbase = S + ((size_t)b*LS_ + (size_t)st*64)*DH_ + dt*64;

  // load 64x64 fp32 tile -> bf16 LDS
  #pragma unroll
  for (int k = 0; k < 4; ++k) {
    int fi  = tid + k*256;
    int row = fi >> 4;          // s within tile
    int c4  = fi & 15;          // float4 within 64 d
    float4 v = *reinterpret_cast<const float4*>(Sbase + (size_t)row*DH_ + c4*4);
    ushort4 h;
    h.x = f2bf(v.x); h.y = f2bf(v.y); h.z = f2bf(v.z); h.w = f2bf(v.w);
    *reinterpret_cast<ushort4*>(&tile[row][c4*4]) = h;
  }
  __syncthreads();

  // ---- Kf: 8x 1KB blocks (wloc 0..1, kkloc 0..3), fully coalesced writes ----
  #pragma unroll
  for (int h2 = 0; h2 < 2; ++h2) {
    int u    = tid + h2*256;        // 0..511
    int blk  = u >> 6;              // 0..7
    int wloc = blk >> 2;            // 0..1
    int kkl  = blk & 3;             // 0..3
    int lane = u & 63;
    int sh   = lane >> 5, sl = lane & 31;
    int srow = wloc*32 + sl;
    int scol = kkl*16 + sh*8;
    ushort4 h0 = *reinterpret_cast<const ushort4*>(&tile[srow][scol]);
    ushort4 h1 = *reinterpret_cast<const ushort4*>(&tile[srow][scol+4]);
    int w_g  = (st & 3)*2 + wloc;
    int kk_g = dt*4 + kkl;
    u8* dst = Kf + (size_t)(((b*16 + t)*8 + w_g)*64 + kk_g)*1024 + lane*16;
    *reinterpret_cast<ushort4*>(dst)     = h0;
    *reinterpret_cast<ushort4*>(dst + 8) = h1;
  }

  // ---- Vf: 8x 1KB blocks (ksloc 0..1, nfloc 0..3), transposed gather ----
  #pragma unroll
  for (int h2 = 0; h2 < 2; ++h2) {
    int u    = tid + h2*256;
    int blk  = u >> 6;
    int ksl  = blk >> 2;            // 0..1
    int nfl  = blk & 3;             // 0..3
    int lane = u & 63;
    int lg   = lane >> 4, lr = lane & 15;
    int srow = ksl*32 + lg*8;
    int dcol = nfl*16 + lr;
    ushort4 h0, h1;
    h0.x = tile[srow+0][dcol]; h0.y = tile[srow+1][dcol];
    h0.z = tile[srow+2][dcol]; h0.w = tile[srow+3][dcol];
    h1.x = tile[srow+4][dcol]; h1.y = tile[srow+5][dcol];
    h1.z = tile[srow+6][dcol]; h1.w = tile[srow+7][dcol];
    int w_g = dt >> 1;
    int i_g = ((st & 3)*2 + ksl)*8 + (dt & 1)*4 + nfl;
    u8* dst = Vf + (size_t)(((b*16 + t)*8 + w_g)*64 + i_g)*1024 + lane*16;
    *reinterpret_cast<ushort4*>(dst)     = h0;
    *reinterpret_cast<ushort4*>(dst + 8) = h1;
  }
}

// ---------------- fused flash attention, m==0 softmax ----------------
// QK^T: 32x32x16 MFMA, Q in lane-linear LDS; K ring from fragment-major ws.
// PV:   16x16x32 MFMA, P via LDS; V ring from fragment-major ws.
__global__ __launch_bounds__(NTH, 2) void attn_kernel(
    const float* __restrict__ Qg,
    const u8* __restrict__ Kf,
    const u8* __restrict__ Vf,
    float* __restrict__ Og)
{
  __shared__ __align__(16) unsigned char qlds[131072];  // [qf:2][kk:64][lane:64]*16B
  __shared__ __align__(16) unsigned char plds[32768];   // P [64 q][256 s] bf16 swizzled

  const int tid = threadIdx.x;
  const int w  = tid >> 6;
  const int l  = tid & 63;
  const int lg = l >> 4;
  const int lr = l & 15;
  const int sl = l & 31;
  const int sh = l >> 5;

  // XCD swizzle: batch -> XCD pair; same-XCD blocks share K/V streams in L2
  const int n    = blockIdx.x;
  const int xcd  = n & 7;
  const int slot = n >> 3;
  const int b    = xcd >> 1;
  const int qt   = (xcd & 1)*32 + slot;

  const float* Qbase = Qg + ((size_t)b*LQ_ + (size_t)qt*BQ_)*DH_;
  // per-thread ring base pointers (wave-contiguous 1KB units)
  const u8* kptr = Kf + (size_t)b*8388608 + (size_t)w*65536 + l*16;
  const u8* vptr = Vf + (size_t)b*8388608 + (size_t)w*65536 + l*16;

  bf16x8 bk[4];
  auto ld_bk = [&](int t, int kk) -> bf16x8 {
    return *reinterpret_cast<const bf16x8*>(kptr + (size_t)t*524288 + kk*1024);
  };
  bf16x8 bv[4];
  auto ld_bv = [&](int t, int ks, int nf) -> bf16x8 {
    return *reinterpret_cast<const bf16x8*>(vptr + (size_t)t*524288 + (ks*8 + nf)*1024);
  };

  // K-ring prologue for t=0 (in flight across Q-stage + barrier)
  bk[0] = ld_bk(0, 0); bk[1] = ld_bk(0, 1); bk[2] = ld_bk(0, 2);

  // ---- stage Q fp32 -> bf16 into lane-linear fragment layout (once) ----
  #pragma unroll
  for (int it = 0; it < 16; ++it) {
    int u  = tid + it*NTH;          // 0..8191 fragment units of 16 B
    int qf = u >> 12;
    int kk = (u >> 6) & 63;
    int ll = u & 63;
    int q  = qf*32 + (ll & 31);
    int d  = kk*16 + (ll >> 5)*8;
    const float* p = Qbase + (size_t)q*DH_ + d;
    f32x4 v0 = *reinterpret_cast<const f32x4*>(p);
    f32x4 v1 = *reinterpret_cast<const f32x4*>(p + 4);
    *reinterpret_cast<bf16x8*>(qlds + (size_t)u*16) = cvt8(v0, v1);
  }

  f32x4 Oacc[4][8];
  #pragma unroll
  for (int i = 0; i < 4; ++i)
    #pragma unroll
    for (int j = 0; j < 8; ++j)
      Oacc[i][j] = (f32x4){0.f, 0.f, 0.f, 0.f};
  f32x4 lacc[4];
  #pragma unroll
  for (int i = 0; i < 4; ++i) lacc[i] = (f32x4){0.f, 0.f, 0.f, 0.f};

  bf16x8 ones;
  #pragma unroll
  for (int e = 0; e < 8; ++e) ones[e] = (__bf16)1.0f;

  WAITL();
  BAR();   // Q staged (global K-ring loads stay in flight)

  for (int t = 0; t < NT_; ++t) {
    // ================= QK^T: C[64 q][wave's 32 s], 32x32x16 =================
    f32x16 qk0, qk1;
    #pragma unroll
    for (int r = 0; r < 16; ++r) { qk0[r] = 0.f; qk1[r] = 0.f; }

    bf16x8 aqA0 = *reinterpret_cast<const bf16x8*>(qlds + l*16);
    bf16x8 aqA1 = *reinterpret_cast<const bf16x8*>(qlds + 65536 + l*16);

    #pragma unroll
    for (int kk = 0; kk < 64; ++kk) {
      if (kk < 61) bk[(kk + 3) & 3] = ld_bk(t, kk + 3);
      bf16x8 aqN0, aqN1;
      if (kk < 63) {
        aqN0 = *reinterpret_cast<const bf16x8*>(qlds + (kk + 1)*1024 + l*16);
        aqN1 = *reinterpret_cast<const bf16x8*>(qlds + 65536 + (kk + 1)*1024 + l*16);
      }
      __builtin_amdgcn_s_setprio(1);
      qk0 = __builtin_amdgcn_mfma_f32_32x32x16_bf16(aqA0, bk[kk & 3], qk0, 0, 0, 0);
      qk1 = __builtin_amdgcn_mfma_f32_32x32x16_bf16(aqA1, bk[kk & 3], qk1, 0, 0, 0);
      __builtin_amdgcn_s_setprio(0);
      if (kk < 63) { aqA0 = aqN0; aqA1 = aqN1; }
    }

    // ================= P = exp2(logit*scl) -> LDS =================
    const float SCL = 0.04508422f;   // (1/32) * log2(e)
    #pragma unroll
    for (int r = 0; r < 16; ++r) {
      int qrow = (r & 3) + 8*(r >> 2) + 4*sh;
      int s    = w*32 + sl;
      {
        float p = exp2f(qk0[r] * SCL);
        int q = qrow;
        *reinterpret_cast<__bf16*>(plds + q*512 + ((s*2) ^ ((q & 7) << 4))) = (__bf16)p;
      }
      {
        float p = exp2f(qk1[r] * SCL);
        int q = 32 + qrow;
        *reinterpret_cast<__bf16*>(plds + q*512 + ((s*2) ^ ((q & 7) << 4))) = (__bf16)p;
      }
    }

    // V-ring prologue (global; independent of P)
    bv[0] = ld_bv(t, 0, 0); bv[1] = ld_bv(t, 0, 1); bv[2] = ld_bv(t, 0, 2);
    WAITL();
    BAR();   // #1: P visible to all waves

    // ================= PV: O[64 q][wave's 128 d] += P[64][256] @ V =================
    bf16x8 pa0, pa1, pa2, pa3, pn0, pn1, pn2, pn3;
    auto ldP = [&](int mq, int ks) -> bf16x8 {
      int q = mq*16 + lr;
      return *reinterpret_cast<const bf16x8*>(
          plds + q*512 + ((ks*64 + lg*16) ^ ((q & 7) << 4)));
    };
    pa0 = ldP(0, 0); pa1 = ldP(1, 0); pa2 = ldP(2, 0); pa3 = ldP(3, 0);

    #pragma unroll
    for (int ks = 0; ks < 8; ++ks) {
      #pragma unroll
      for (int nf = 0; nf < 8; ++nf) {
        const int i = ks*8 + nf;
        if (i < 61) bv[(i + 3) & 3] = ld_bv(t, (i + 3) >> 3, (i + 3) & 7);
        if (t + 1 < NT_ && i >= 61) bk[i - 61] = ld_bk(t + 1, i - 61);
        if (ks < 7) {
          if (nf == 1) pn0 = ldP(0, ks + 1);
          if (nf == 2) pn1 = ldP(1, ks + 1);
          if (nf == 3) pn2 = ldP(2, ks + 1);
          if (nf == 4) pn3 = ldP(3, ks + 1);
        }
        if (nf == 0 && w == 0) {
          lacc[0] = __builtin_amdgcn_mfma_f32_16x16x32_bf16(pa0, ones, lacc[0], 0, 0, 0);
          lacc[1] = __builtin_amdgcn_mfma_f32_16x16x32_bf16(pa1, ones, lacc[1], 0, 0, 0);
          lacc[2] = __builtin_amdgcn_mfma_f32_16x16x32_bf16(pa2, ones, lacc[2], 0, 0, 0);
          lacc[3] = __builtin_amdgcn_mfma_f32_16x16x32_bf16(pa3, ones, lacc[3], 0, 0, 0);
        }
        __builtin_amdgcn_s_setprio(1);
        Oacc[0][nf] = __builtin_amdgcn_mfma_f32_16x16x32_bf16(pa0, bv[i & 3], Oacc[0][nf], 0, 0, 0);
        Oacc[1][nf] = __builtin_amdgcn_mfma_f32_16x16x32_bf16(pa1, bv[i & 3], Oacc[1][nf], 0, 0, 0);
        Oacc[2][nf] = __builtin_amdgcn_mfma_f32_16x16x32_bf16(pa2, bv[i & 3], Oacc[2][nf], 0, 0, 0);
        Oacc[3][nf] = __builtin_amdgcn_mfma_f32_16x16x32_bf16(pa3, bv[i & 3], Oacc[3][nf], 0, 0, 0);
        __builtin_amdgcn_s_setprio(0);
      }
      if (ks < 7) { pa0 = pn0; pa1 = pn1; pa2 = pn2; pa3 = pn3; }
    }
    BAR();   // #2: P region free for next tile's writes
  }

  // ================= epilogue: l from wave-0 ones-MFMA, write O =================
  float* lred = (float*)plds;
  if (w == 0 && lr == 0) {
    #pragma unroll
    for (int mq = 0; mq < 4; ++mq)
      #pragma unroll
      for (int j = 0; j < 4; ++j)
        lred[mq*16 + lg*4 + j] = lacc[mq][j];
  }
  WAITL();
  BAR();

  float* Ob = Og + ((size_t)b*LQ_ + (size_t)qt*BQ_)*DH_;
  #pragma unroll
  for (int mq = 0; mq < 4; ++mq)
    #pragma unroll
    for (int j = 0; j < 4; ++j) {
      int q = mq*16 + lg*4 + j;
      float rinv = 1.0f / lred[q];
      #pragma unroll
      for (int nf = 0; nf < 8; ++nf)
        Ob[(size_t)q*DH_ + w*128 + nf*16 + lr] = Oacc[mq][nf][j] * rinv;
    }
}

// ---------------- correctness-only fallback (ws too small; never expected) ----------------
__global__ void attn_naive(const float* __restrict__ Q, const float* __restrict__ S,
                           float* __restrict__ O)
{
  const int row = blockIdx.x;
  const int b = row >> 12, q = row & 4095;
  const float* qp = Q + ((size_t)b*LQ_ + q)*DH_;
  const float* sp = S + (size_t)b*LS_*DH_;
  __shared__ float qs[DH_];
  __shared__ float osum[DH_];
  __shared__ float lsum;
  for (int i = threadIdx.x; i < DH_; i += 256) { qs[i] = qp[i]; osum[i] = 0.f; }
  if (threadIdx.x == 0) lsum = 0.f;
  __syncthreads();
  float lpart = 0.f;
  for (int s0 = threadIdx.x; s0 < LS_; s0 += 256) {
    const float* sr = sp + (size_t)s0*DH_;
    float dot = 0.f;
    for (int d = 0; d < DH_; ++d) dot += qs[d]*sr[d];
    float p = __expf(dot * 0.03125f);
    lpart += p;
    for (int d = 0; d < DH_; ++d) atomicAdd(&osum[d], p*sr[d]);
  }
  atomicAdd(&lsum, lpart);
  __syncthreads();
  float rinv = 1.0f / lsum;
  float* op = O + ((size_t)b*LQ_ + q)*DH_;
  for (int i = threadIdx.x; i < DH_; i += 256) op[i] = osum[i]*rinv;
}

extern "C" void kernel_launch(void* const* d_in, const int* in_sizes, int n_in,
                              void* d_out, int out_size, void* d_ws, size_t ws_size,
                              hipStream_t stream)
{
  const float* Q = (const float*)d_in[0];
  const float* S = (const float*)d_in[1];
  float* out = (float*)d_out;

  const size_t kf_bytes = (size_t)B_*NT_*8*64*1024;   // 32 MiB
  const size_t vf_bytes = (size_t)B_*NT_*8*64*1024;   // 32 MiB
  const size_t need = kf_bytes + vf_bytes;            // 64 MiB

  if (ws_size >= need) {
    u8* Kf = (u8*)d_ws;
    u8* Vf = Kf + kf_bytes;
    cvt_kernel<<<dim3(64, 16, 4), 256, 0, stream>>>(S, Kf, Vf);
    attn_kernel<<<dim3(256), NTH, 0, stream>>>(Q, Kf, Vf, out);
  } else {
    attn_naive<<<dim3(B_*LQ_), 256, 0, stream>>>(Q, S, out);
  }
}